// Round 1
// baseline (783.930 us; speedup 1.0000x reference)
//
#include <hip/hip_runtime.h>
#include <hip/hip_cooperative_groups.h>

namespace cg = cooperative_groups;

constexpr int EMB  = 128;   // EMB_DIM
constexpr int H1D  = 256;   // 2*HIDDEN
constexpr int H2D  = 128;   // HIDDEN
constexpr int VOC  = 4096;  // VOCAB
constexpr int NSL  = 32;    // wsum slices (atomic-contention spreading)
constexpr int RPB  = 16;    // emb rows per tile in embW1 GEMM
constexpr int GB   = 1024;  // cooperative grid: 4 blocks/CU * 256 CUs
constexpr int BE   = 256;   // phase-1 blocks assigned to embW1 (rest do hist)

struct Params {
    const int*   x;
    const int*   row;
    const int*   col;
    const int*   xpos;
    const float* emb;
    const float* W1;
    const float* b1;
    const float* W2;
    const float* b2;
    const float* Wc;
    const float* bc;
    float*       out;
    int*          cnt;
    int*          offs;
    int*          cursor;
    int*          count;
    int*          needlist;
    unsigned int* needw;
    unsigned int* flagbits;
    int2*         srowp;
    int*          nflag;
    int*          total;
    float*        wagg;
    float*        embW1;
    float*        wsum;
    int   n, ne, np, nwords, nceil;
    float inv_np;
};

// ============================================================================
// Fused cooperative pipeline. Phases separated by grid.sync():
//   P0: zero state; block 0 builds flagbits from x_position
//   P1: blocks [0,BE) compute embW1 = emb@W1  ||  blocks [BE,G) edge histogram
//       + needed-row marks (block 0 also accumulates x_position multiplicities)
//   P2: alloc — canonical needbits via ballot, CSR bump-alloc, wagg self term
//   P3: scatter needed edges -> packed {x[row], dinv[row]}, wagg edge terms
//   P4: fused conv1+conv2 gather over needed nodes -> wsum slices
//   P5: head — reduce slices, zmean@W2, @Wc (blocks 0..15)
// __launch_bounds__(256,4): <=128 VGPR => 4 blocks/CU => GB=1024 co-resident.
// ============================================================================
__global__ __launch_bounds__(256, 4) void k_all(Params P) {
    cg::grid_group grid = cg::this_grid();
    const int tid  = threadIdx.x;
    const int bid  = blockIdx.x;
    const int G    = gridDim.x;
    const int lane = tid & 63;

    __shared__ float smem[RPB * EMB];   // 8 KB, reused by P1 / P4 / P5

    // ---------------- Phase 0: init + flagbits ----------------
    if (bid == 0) {
        for (int i = tid; i < P.nwords; i += 256) P.flagbits[i] = 0u;
        __syncthreads();
        for (int i = tid; i < P.np; i += 256) {
            int v = P.xpos[i];
            atomicOr(&P.flagbits[v >> 5], 1u << (v & 31));
        }
        if (tid == 0) { *P.nflag = 0; *P.total = 0; }
    } else {
        const int stride = (G - 1) * 256;
        const int i0 = (bid - 1) * 256 + tid;
        for (int i = i0; i < P.n; i += stride) {
            P.cnt[i] = 0; P.count[i] = 0; P.wagg[i] = 0.0f;
        }
        for (int i = i0; i < P.nwords; i += stride) P.needw[i] = 0u;
        for (int i = i0; i < NSL * H1D; i += stride) P.wsum[i] = 0.0f;
    }
    grid.sync();

    // ---------------- Phase 1: embW1 GEMM || histogram+mark ----------------
    if (bid < BE) {
        if (bid == 0) {   // x_position multiplicities (count[] zeroed in P0)
            for (int i = tid; i < P.np; i += 256) atomicAdd(&P.count[P.xpos[i]], 1);
        }
        float (*er)[EMB] = (float (*)[EMB])smem;
        for (int tile = bid; tile < VOC / RPB; tile += BE) {
            int r0 = tile * RPB;
            for (int i = tid; i < RPB * EMB; i += 256)
                er[i / EMB][i % EMB] = P.emb[(size_t)r0 * EMB + i];
            __syncthreads();
            float acc[RPB];
#pragma unroll
            for (int rr = 0; rr < RPB; rr++) acc[rr] = 0.0f;
            for (int k = 0; k < EMB; k++) {
                float w = P.W1[k * H1D + tid];
#pragma unroll
                for (int rr = 0; rr < RPB; rr++) acc[rr] += er[rr][k] * w;
            }
#pragma unroll
            for (int rr = 0; rr < RPB; rr++)
                P.embW1[(size_t)(r0 + rr) * H1D + tid] = acc[rr];
            __syncthreads();
        }
    } else {
        const int stride = (G - BE) * 256;
        for (int e = (bid - BE) * 256 + tid; e < P.ne; e += stride) {
            int c = P.col[e];
            atomicAdd(&P.cnt[c], 1);
            if ((P.flagbits[c >> 5] >> (c & 31)) & 1u) {   // ~2% of edges
                int r = P.row[e];
                atomicOr(&P.needw[r >> 5], 1u << (r & 31));
            }
        }
    }
    grid.sync();

    // ---------------- Phase 2: alloc (wave-aligned chunks) ----------------
    for (int base = bid * 256; base < P.nceil; base += G * 256) {
        int v = base + tid;
        int cv = 0;
        bool need = false;
        if (v < P.n) {
            cv = P.cnt[v];
            bool mark = (P.needw[v >> 5] >> (v & 31)) & 1u;
            bool flag = (P.flagbits[v >> 5] >> (v & 31)) & 1u;
            need = mark || flag;
            if (flag) P.wagg[v] = (float)P.count[v] / ((float)cv + 1.0f);
        }
        // canonical needbits: ballot -> one word per half-wave, store by owner
        unsigned long long nm = __ballot(need);
        int wbase = (v & ~63) >> 5;
        if (lane == 0)  P.needw[wbase]     = (unsigned int)(nm & 0xffffffffu);
        if (lane == 32) P.needw[wbase + 1] = (unsigned int)(nm >> 32);
        int seg = need ? cv : 0;
        int incl = seg;
#pragma unroll
        for (int d = 1; d < 64; d <<= 1) {
            int t2 = __shfl_up(incl, d);
            if (lane >= d) incl += t2;
        }
        int excl = incl - seg;
        int wave_total = __shfl(incl, 63);
        int rank = __popcll(nm & ((1ull << lane) - 1));
        int wcnt = __popcll(nm);
        int base_id = 0, base_off = 0;
        if (lane == 0) {
            if (wcnt > 0)       base_id  = atomicAdd(P.nflag, wcnt);
            if (wave_total > 0) base_off = atomicAdd(P.total, wave_total);
        }
        base_id  = __shfl(base_id, 0);
        base_off = __shfl(base_off, 0);
        if (need) {
            P.needlist[base_id + rank] = v;
            int o = base_off + excl;
            P.offs[v]   = o;
            P.cursor[v] = o;
        }
    }
    grid.sync();

    // ---------------- Phase 3: scatter (filtered to needed cols) ----------------
    for (int e = bid * 256 + tid; e < P.ne; e += G * 256) {
        int c = P.col[e];
        if ((P.needw[c >> 5] >> (c & 31)) & 1u) {
            int r = P.row[e];
            int pos = atomicAdd(&P.cursor[c], 1);
            float dr = rsqrtf((float)P.cnt[r] + 1.0f);
            int2 pk; pk.x = P.x[r]; pk.y = __float_as_int(dr);
            P.srowp[pos] = pk;
            if ((P.flagbits[c >> 5] >> (c & 31)) & 1u) {   // ~2% of edges
                float dc = rsqrtf((float)P.cnt[c] + 1.0f);
                atomicAdd(&P.wagg[r], (float)P.count[c] * dc * dr);
            }
        }
    }
    grid.sync();

    // ---------------- Phase 4: fused conv1+conv2 over needed nodes ----------------
    {
        const int wib = tid >> 6;
        const int wid = bid * 4 + wib;
        const int nw  = G * 4;
        const int nn  = *P.nflag;
        const float4* __restrict__ ew = (const float4*)P.embW1;   // row r = ew + r*64
        float4 bfrag = ((const float4*)P.b1)[lane];
        float4 acc2 = {0.0f, 0.0f, 0.0f, 0.0f};

        for (int i = wid; i < nn; i += nw) {
            int v  = P.needlist[i];
            int cv = P.cnt[v];
            float dv = rsqrtf((float)cv + 1.0f);
            float wa = P.wagg[v];
            float4 s = ew[(size_t)P.x[v] * 64 + lane];
            float w0 = dv * dv;
            float4 acc;
            acc.x = bfrag.x + w0 * s.x;
            acc.y = bfrag.y + w0 * s.y;
            acc.z = bfrag.z + w0 * s.z;
            acc.w = bfrag.w + w0 * s.w;
            int start = P.offs[v], m = cv;
            for (int base = 0; base < m; base += 64) {
                int mm = min(64, m - base);
                int xr = 0; float wr = 0.0f;
                if (lane < mm) {
                    int2 pk = P.srowp[start + base + lane];   // one 8B load
                    xr = pk.x;
                    wr = __int_as_float(pk.y) * dv;
                }
                int e = 0;
                for (; e + 4 <= mm; e += 4) {
                    int i0 = __shfl(xr, e),     i1 = __shfl(xr, e + 1);
                    int i2 = __shfl(xr, e + 2), i3 = __shfl(xr, e + 3);
                    float q0 = __shfl(wr, e),     q1 = __shfl(wr, e + 1);
                    float q2 = __shfl(wr, e + 2), q3 = __shfl(wr, e + 3);
                    float4 t0 = ew[(size_t)i0 * 64 + lane];
                    float4 t1 = ew[(size_t)i1 * 64 + lane];
                    float4 t2 = ew[(size_t)i2 * 64 + lane];
                    float4 t3 = ew[(size_t)i3 * 64 + lane];
                    acc.x += q0 * t0.x + q1 * t1.x + q2 * t2.x + q3 * t3.x;
                    acc.y += q0 * t0.y + q1 * t1.y + q2 * t2.y + q3 * t3.y;
                    acc.z += q0 * t0.z + q1 * t1.z + q2 * t2.z + q3 * t3.z;
                    acc.w += q0 * t0.w + q1 * t1.w + q2 * t2.w + q3 * t3.w;
                }
                for (; e < mm; e++) {
                    int i0 = __shfl(xr, e);
                    float q0 = __shfl(wr, e);
                    float4 t0 = ew[(size_t)i0 * 64 + lane];
                    acc.x += q0 * t0.x;
                    acc.y += q0 * t0.y;
                    acc.z += q0 * t0.z;
                    acc.w += q0 * t0.w;
                }
            }
            acc2.x += wa * fmaxf(acc.x, 0.0f);
            acc2.y += wa * fmaxf(acc.y, 0.0f);
            acc2.z += wa * fmaxf(acc.z, 0.0f);
            acc2.w += wa * fmaxf(acc.w, 0.0f);
        }

        float (*red)[H1D] = (float (*)[H1D])smem;   // 4 KB of the 8 KB buffer
        red[wib][4 * lane + 0] = acc2.x;
        red[wib][4 * lane + 1] = acc2.y;
        red[wib][4 * lane + 2] = acc2.z;
        red[wib][4 * lane + 3] = acc2.w;
        __syncthreads();
        float ssum = red[0][tid] + red[1][tid] + red[2][tid] + red[3][tid];
        atomicAdd(&P.wsum[(bid & (NSL - 1)) * H1D + tid], ssum);
    }
    grid.sync();

    // ---------------- Phase 5: head (blocks 0..15) ----------------
    if (bid < VOC / 256) {
        float* ws = smem;         // 256 floats
        float* z  = smem + H1D;   // 128 floats
        float s = 0.0f;
#pragma unroll
        for (int c2 = 0; c2 < NSL; c2++) s += P.wsum[c2 * H1D + tid];
        ws[tid] = s;
        __syncthreads();
        if (tid < H2D) {
            float acc = 0.0f;
#pragma unroll 8
            for (int k = 0; k < H1D; k++) acc += ws[k] * P.W2[k * H2D + tid];
            z[tid] = P.b2[tid] + acc * P.inv_np;
        }
        __syncthreads();
        int c = bid * 256 + tid;
        float acc = P.bc[c];
#pragma unroll 8
        for (int j = 0; j < H2D; j++) acc += z[j] * P.Wc[(size_t)j * VOC + c];
        P.out[c] = acc;
    }
}

// ============================================================================
// Legacy 7-kernel fallback (verbatim from the proven 193µs version), used only
// if the cooperative launch is rejected by the runtime.
// ============================================================================
__global__ void k_init(int* cnt, int* count, unsigned int* flagbits, unsigned int* markw,
                       float* wagg, float* wsum, int* nflag, int* total,
                       int n, int nwords) {
    int i = blockIdx.x * blockDim.x + threadIdx.x;
    if (i < n) { cnt[i] = 0; count[i] = 0; wagg[i] = 0.0f; }
    if (i < nwords) { flagbits[i] = 0u; markw[i] = 0u; }
    if (i < NSL * H1D) wsum[i] = 0.0f;
    if (i == 0) { *nflag = 0; *total = 0; }
}

__global__ void k_embW1C(const float* __restrict__ emb, const float* __restrict__ W1,
                         float* __restrict__ embW1,
                         const int* __restrict__ xpos, int* count,
                         unsigned int* flagbits, int np) {
    int t = threadIdx.x;
    if (blockIdx.x == VOC / RPB) {
        for (int p = t; p < np; p += blockDim.x) {
            int v = xpos[p];
            atomicAdd(&count[v], 1);
            atomicOr(&flagbits[v >> 5], 1u << (v & 31));
        }
        return;
    }
    __shared__ float er[RPB][EMB];
    int r0 = blockIdx.x * RPB;
    for (int i = t; i < RPB * EMB; i += 256) {
        er[i / EMB][i % EMB] = emb[(size_t)r0 * EMB + i];
    }
    __syncthreads();
    float acc[RPB];
#pragma unroll
    for (int rr = 0; rr < RPB; rr++) acc[rr] = 0.0f;
    for (int k = 0; k < EMB; k++) {
        float w = W1[k * H1D + t];
#pragma unroll
        for (int rr = 0; rr < RPB; rr++) acc[rr] += er[rr][k] * w;
    }
#pragma unroll
    for (int rr = 0; rr < RPB; rr++) {
        embW1[(size_t)(r0 + rr) * H1D + t] = acc[rr];
    }
}

__global__ void k_hist(const int* __restrict__ row, const int* __restrict__ col,
                       const unsigned int* __restrict__ flagbits, int* cnt,
                       unsigned int* markw, int ne) {
    int e = blockIdx.x * blockDim.x + threadIdx.x;
    if (e < ne) {
        int c = col[e];
        atomicAdd(&cnt[c], 1);
        if ((flagbits[c >> 5] >> (c & 31)) & 1u) {
            int r = row[e];
            atomicOr(&markw[r >> 5], 1u << (r & 31));
        }
    }
}

__global__ void k_alloc(unsigned int* needw,
                        const unsigned int* __restrict__ flagbits,
                        const int* __restrict__ cnt, const int* __restrict__ count,
                        float* wagg, int* needlist, int* nflag, int* total,
                        int* offs, int* cursor, int n) {
    int v = blockIdx.x * blockDim.x + threadIdx.x;
    int lane = threadIdx.x & 63;
    int cv = 0;
    bool need = false;
    if (v < n) {
        cv = cnt[v];
        bool mark = (needw[v >> 5] >> (v & 31)) & 1u;
        bool flag = (flagbits[v >> 5] >> (v & 31)) & 1u;
        need = mark || flag;
        if (flag) wagg[v] = (float)count[v] / ((float)cv + 1.0f);
    }
    unsigned long long nm = __ballot(need);
    int wbase = (v & ~63) >> 5;
    if (lane == 0)  needw[wbase]     = (unsigned int)(nm & 0xffffffffu);
    if (lane == 32) needw[wbase + 1] = (unsigned int)(nm >> 32);
    int seg = need ? cv : 0;
    int incl = seg;
#pragma unroll
    for (int d = 1; d < 64; d <<= 1) {
        int t = __shfl_up(incl, d);
        if (lane >= d) incl += t;
    }
    int excl = incl - seg;
    int wave_total = __shfl(incl, 63);
    int rank = __popcll(nm & ((1ull << lane) - 1));
    int wcnt = __popcll(nm);
    int base_id = 0, base_off = 0;
    if (lane == 0) {
        if (wcnt > 0) base_id = atomicAdd(nflag, wcnt);
        if (wave_total > 0) base_off = atomicAdd(total, wave_total);
    }
    base_id  = __shfl(base_id, 0);
    base_off = __shfl(base_off, 0);
    if (need) {
        needlist[base_id + rank] = v;
        int o = base_off + excl;
        offs[v] = o;
        cursor[v] = o;
    }
}

__global__ void k_scatter(const int* __restrict__ row, const int* __restrict__ col,
                          const unsigned int* __restrict__ needw,
                          const unsigned int* __restrict__ flagbits,
                          const int* __restrict__ count,
                          const int* __restrict__ x, const int* __restrict__ cnt,
                          int* cursor, int2* srowp, float* wagg, int ne) {
    int e = blockIdx.x * blockDim.x + threadIdx.x;
    if (e < ne) {
        int c = col[e];
        if ((needw[c >> 5] >> (c & 31)) & 1u) {
            int r = row[e];
            int pos = atomicAdd(&cursor[c], 1);
            float dr = rsqrtf((float)cnt[r] + 1.0f);
            int2 pk; pk.x = x[r]; pk.y = __float_as_int(dr);
            srowp[pos] = pk;
            if ((flagbits[c >> 5] >> (c & 31)) & 1u) {
                float dc = rsqrtf((float)cnt[c] + 1.0f);
                atomicAdd(&wagg[r], (float)count[c] * dc * dr);
            }
        }
    }
}

__global__ void k_fconv(const int* __restrict__ needlist, const int* __restrict__ nneed_p,
                        const float* __restrict__ wagg, const int* __restrict__ x,
                        const int2* __restrict__ srowp,
                        const int* __restrict__ offs, const int* __restrict__ cnt,
                        const float* __restrict__ embW1, const float* __restrict__ b1,
                        float* __restrict__ wsum) {
    int lane = threadIdx.x & 63;
    int wib  = threadIdx.x >> 6;
    int wid  = blockIdx.x * (blockDim.x >> 6) + wib;
    int nw   = gridDim.x * (blockDim.x >> 6);
    int nn   = *nneed_p;
    const float4* __restrict__ ew = (const float4*)embW1;
    float4 bfrag = ((const float4*)b1)[lane];
    float4 acc2 = {0.0f, 0.0f, 0.0f, 0.0f};

    for (int i = wid; i < nn; i += nw) {
        int v = needlist[i];
        int cv = cnt[v];
        float dv = rsqrtf((float)cv + 1.0f);
        float wa = wagg[v];
        float4 s = ew[(size_t)x[v] * 64 + lane];
        float w0 = dv * dv;
        float4 acc;
        acc.x = bfrag.x + w0 * s.x;
        acc.y = bfrag.y + w0 * s.y;
        acc.z = bfrag.z + w0 * s.z;
        acc.w = bfrag.w + w0 * s.w;
        int start = offs[v], m = cv;
        for (int base = 0; base < m; base += 64) {
            int mm = min(64, m - base);
            int xr = 0; float wr = 0.0f;
            if (lane < mm) {
                int2 pk = srowp[start + base + lane];
                xr = pk.x;
                wr = __int_as_float(pk.y) * dv;
            }
            int e = 0;
            for (; e + 4 <= mm; e += 4) {
                int i0 = __shfl(xr, e),     i1 = __shfl(xr, e + 1);
                int i2 = __shfl(xr, e + 2), i3 = __shfl(xr, e + 3);
                float q0 = __shfl(wr, e),     q1 = __shfl(wr, e + 1);
                float q2 = __shfl(wr, e + 2), q3 = __shfl(wr, e + 3);
                float4 t0 = ew[(size_t)i0 * 64 + lane];
                float4 t1 = ew[(size_t)i1 * 64 + lane];
                float4 t2 = ew[(size_t)i2 * 64 + lane];
                float4 t3 = ew[(size_t)i3 * 64 + lane];
                acc.x += q0 * t0.x + q1 * t1.x + q2 * t2.x + q3 * t3.x;
                acc.y += q0 * t0.y + q1 * t1.y + q2 * t2.y + q3 * t3.y;
                acc.z += q0 * t0.z + q1 * t1.z + q2 * t2.z + q3 * t3.z;
                acc.w += q0 * t0.w + q1 * t1.w + q2 * t2.w + q3 * t3.w;
            }
            for (; e < mm; e++) {
                int i0 = __shfl(xr, e);
                float q0 = __shfl(wr, e);
                float4 t0 = ew[(size_t)i0 * 64 + lane];
                acc.x += q0 * t0.x;
                acc.y += q0 * t0.y;
                acc.z += q0 * t0.z;
                acc.w += q0 * t0.w;
            }
        }
        acc2.x += wa * fmaxf(acc.x, 0.0f);
        acc2.y += wa * fmaxf(acc.y, 0.0f);
        acc2.z += wa * fmaxf(acc.z, 0.0f);
        acc2.w += wa * fmaxf(acc.w, 0.0f);
    }

    __shared__ float red[4][H1D];
    red[wib][4 * lane + 0] = acc2.x;
    red[wib][4 * lane + 1] = acc2.y;
    red[wib][4 * lane + 2] = acc2.z;
    red[wib][4 * lane + 3] = acc2.w;
    __syncthreads();
    int t = threadIdx.x;
    float ssum = red[0][t] + red[1][t] + red[2][t] + red[3][t];
    atomicAdd(&wsum[(blockIdx.x & (NSL - 1)) * H1D + t], ssum);
}

__global__ void k_zout(const float* __restrict__ wsum, const float* __restrict__ W2,
                       const float* __restrict__ b2, const float* __restrict__ Wc,
                       const float* __restrict__ bc, float* __restrict__ out,
                       float inv_np) {
    __shared__ float ws[H1D];
    __shared__ float z[H2D];
    int t = threadIdx.x;
    float s = 0.0f;
#pragma unroll
    for (int c = 0; c < NSL; c++) s += wsum[c * H1D + t];
    ws[t] = s;
    __syncthreads();
    if (t < H2D) {
        float acc = 0.0f;
#pragma unroll 8
        for (int k = 0; k < H1D; k++) acc += ws[k] * W2[k * H2D + t];
        z[t] = b2[t] + acc * inv_np;
    }
    __syncthreads();
    int c = blockIdx.x * blockDim.x + t;
    float acc = bc[c];
#pragma unroll 8
    for (int j = 0; j < H2D; j++) acc += z[j] * Wc[(size_t)j * VOC + c];
    out[c] = acc;
}

extern "C" void kernel_launch(void* const* d_in, const int* in_sizes, int n_in,
                              void* d_out, int out_size, void* d_ws, size_t ws_size,
                              hipStream_t stream) {
    const int n  = in_sizes[0];
    const int ne = in_sizes[1] / 2;
    const int np = in_sizes[2];

    const int*   x    = (const int*)d_in[0];
    const int*   ei   = (const int*)d_in[1];
    const int*   xpos = (const int*)d_in[2];
    const float* emb  = (const float*)d_in[3];
    const float* W1   = (const float*)d_in[4];
    const float* b1   = (const float*)d_in[5];
    const float* W2   = (const float*)d_in[6];
    const float* b2   = (const float*)d_in[7];
    const float* Wc   = (const float*)d_in[8];
    const float* bc   = (const float*)d_in[9];
    float*       out  = (float*)d_out;

    const int* row = ei;       // edge_index[0]
    const int* col = ei + ne;  // edge_index[1]

    char* p = (char*)d_ws;
    auto alloc = [&](size_t bytes) {
        char* r = p;
        p += (bytes + 255) & ~(size_t)255;
        return r;
    };
    const int nb     = (n + 255) / 256;
    const int neb    = (ne + 255) / 256;
    const int nwords = nb * 8;   // (nb*256)/32 — padded so ballot stores stay in-bounds

    int*          cnt      = (int*)alloc((size_t)n * 4);
    int*          offs     = (int*)alloc((size_t)n * 4);
    int*          cursor   = (int*)alloc((size_t)n * 4);
    int*          count    = (int*)alloc((size_t)n * 4);
    int*          needlist = (int*)alloc((size_t)n * 4);
    unsigned int* needw    = (unsigned int*)alloc((size_t)nwords * 4);
    unsigned int* flagbits = (unsigned int*)alloc((size_t)nwords * 4);
    int2*         srowp    = (int2*)alloc((size_t)ne * 8);
    int*          nflag    = (int*)alloc(256 * 4);
    int*          total    = (int*)alloc(256 * 4);
    float*        wagg     = (float*)alloc((size_t)n * 4);
    float*        embW1    = (float*)alloc((size_t)VOC * H1D * 4);
    float*        wsum     = (float*)alloc((size_t)NSL * H1D * 4);

    Params P;
    P.x = x; P.row = row; P.col = col; P.xpos = xpos;
    P.emb = emb; P.W1 = W1; P.b1 = b1; P.W2 = W2; P.b2 = b2; P.Wc = Wc; P.bc = bc;
    P.out = out;
    P.cnt = cnt; P.offs = offs; P.cursor = cursor; P.count = count;
    P.needlist = needlist; P.needw = needw; P.flagbits = flagbits;
    P.srowp = srowp; P.nflag = nflag; P.total = total;
    P.wagg = wagg; P.embW1 = embW1; P.wsum = wsum;
    P.n = n; P.ne = ne; P.np = np; P.nwords = nwords; P.nceil = nb * 256;
    P.inv_np = 1.0f / (float)np;

    void* kargs[] = { (void*)&P };
    hipError_t err = hipLaunchCooperativeKernel((const void*)k_all, dim3(GB), dim3(256),
                                                kargs, 0, stream);
    if (err != hipSuccess) {
        // Fallback: proven 7-kernel pipeline
        k_init<<<nb, 256, 0, stream>>>(cnt, count, flagbits, needw, wagg, wsum,
                                       nflag, total, n, nwords);
        k_embW1C<<<VOC / RPB + 1, 256, 0, stream>>>(emb, W1, embW1, xpos, count, flagbits, np);
        k_hist<<<neb, 256, 0, stream>>>(row, col, flagbits, cnt, needw, ne);
        k_alloc<<<nb, 256, 0, stream>>>(needw, flagbits, cnt, count, wagg,
                                        needlist, nflag, total, offs, cursor, n);
        k_scatter<<<neb, 256, 0, stream>>>(row, col, needw, flagbits, count, x, cnt,
                                           cursor, srowp, wagg, ne);
        k_fconv<<<2048, 256, 0, stream>>>(needlist, nflag, wagg, x, srowp, offs, cnt,
                                          embW1, b1, wsum);
        k_zout<<<VOC / 256, 256, 0, stream>>>(wsum, W2, b2, Wc, bc, out, 1.0f / (float)np);
    }
}

// Round 2
// 187.659 us; speedup vs baseline: 4.1774x; 4.1774x over previous
//
#include <hip/hip_runtime.h>

constexpr int EMB  = 128;   // EMB_DIM
constexpr int H1D  = 256;   // 2*HIDDEN
constexpr int H2D  = 128;   // HIDDEN
constexpr int VOC  = 4096;  // VOCAB
constexpr int NSL  = 32;    // wsum slices (atomic-contention spreading)
constexpr int RPB  = 16;    // emb rows per tile in embW1 GEMM

// ---------------- kA: zero state; block 0 builds flagbits + count from x_position.
// flagbits/count are zeroed and atomically built inside the SAME block (block 0),
// so there is no cross-block ordering hazard.
__global__ void kA_init(int* cnt, int* count, unsigned int* flagbits, unsigned int* needw,
                        float* wagg, float* wsum, int* nflag, int* total,
                        const int* __restrict__ xpos,
                        int n, int nwords, int np) {
    int t = threadIdx.x;
    if (blockIdx.x == 0) {
        for (int i = t; i < nwords; i += 256) flagbits[i] = 0u;
        for (int i = t; i < n; i += 256) count[i] = 0;
        __syncthreads();
        for (int i = t; i < np; i += 256) {
            int v = xpos[i];
            atomicAdd(&count[v], 1);
            atomicOr(&flagbits[v >> 5], 1u << (v & 31));
        }
        if (t == 0) { *nflag = 0; *total = 0; }
    } else {
        const int stride = (gridDim.x - 1) * 256;
        const int i0 = (blockIdx.x - 1) * 256 + t;
        for (int i = i0; i < n; i += stride) { cnt[i] = 0; wagg[i] = 0.0f; }
        for (int i = i0; i < nwords; i += stride) needw[i] = 0u;
        for (int i = i0; i < NSL * H1D; i += stride) wsum[i] = 0.0f;
    }
}

// ---------------- kB: blocks [0,256) embW1 = emb @ W1 (one 16-row tile each)
//                   || blocks [256,1024) in-degree histogram + needed-row marks.
// The two jobs are independent (hist reads flagbits built by kA); running them
// in one dispatch overlaps a latency-bound GEMM with an atomic-bound sweep.
constexpr int KB_GRID = 1024;
constexpr int GEMM_B  = 256;
__global__ __launch_bounds__(256) void kB_embW1_hist(
        const float* __restrict__ emb, const float* __restrict__ W1,
        float* __restrict__ embW1,
        const int* __restrict__ row, const int* __restrict__ col,
        const unsigned int* __restrict__ flagbits,
        int* cnt, unsigned int* markw, int ne) {
    int t = threadIdx.x;
    if (blockIdx.x < GEMM_B) {
        __shared__ float er[RPB][EMB];   // 8 KB
        int r0 = blockIdx.x * RPB;
        for (int i = t; i < RPB * EMB; i += 256)
            er[i / EMB][i % EMB] = emb[(size_t)r0 * EMB + i];
        __syncthreads();
        float acc[RPB];
#pragma unroll
        for (int rr = 0; rr < RPB; rr++) acc[rr] = 0.0f;
        for (int k = 0; k < EMB; k++) {
            float w = W1[k * H1D + t];
#pragma unroll
            for (int rr = 0; rr < RPB; rr++) acc[rr] += er[rr][k] * w;
        }
#pragma unroll
        for (int rr = 0; rr < RPB; rr++)
            embW1[(size_t)(r0 + rr) * H1D + t] = acc[rr];
    } else {
        const int stride = (KB_GRID - GEMM_B) * 256;
        for (int e = (blockIdx.x - GEMM_B) * 256 + t; e < ne; e += stride) {
            int c = col[e];
            atomicAdd(&cnt[c], 1);
            if ((flagbits[c >> 5] >> (c & 31)) & 1u) {   // ~2% of edges
                int r = row[e];
                atomicOr(&markw[r >> 5], 1u << (r & 31));
            }
        }
    }
}

// ------- k_alloc: need = mark||flag; canonical needbits via wave-ballot plain store;
//         CSR bump-alloc (wave-aggregated atomics); wagg self term;
//         NEW: packed pk[v] = {x[v], rsqrt(cnt[v]+1)} so scatter does 1 gather not 2.
__global__ void k_alloc(unsigned int* needw,
                        const unsigned int* __restrict__ flagbits,
                        const int* __restrict__ cnt, const int* __restrict__ count,
                        const int* __restrict__ x,
                        float* wagg, int* needlist, int* nflag, int* total,
                        int* offs, int* cursor, int2* pk, int n) {
    int v = blockIdx.x * blockDim.x + threadIdx.x;
    int lane = threadIdx.x & 63;
    int cv = 0;
    bool need = false;
    if (v < n) {
        cv = cnt[v];
        float dv = rsqrtf((float)cv + 1.0f);
        int2 p; p.x = x[v]; p.y = __float_as_int(dv);
        pk[v] = p;
        bool mark = (needw[v >> 5] >> (v & 31)) & 1u;
        bool flag = (flagbits[v >> 5] >> (v & 31)) & 1u;
        need = mark || flag;
        if (flag) wagg[v] = (float)count[v] / ((float)cv + 1.0f);  // count*dinv^2
    }
    // canonical needbits: ballot -> one word per half-wave, plain store by owner lane
    unsigned long long nm = __ballot(need);
    int wbase = (v & ~63) >> 5;            // v is wave-aligned at lane 0
    if (lane == 0)  needw[wbase]     = (unsigned int)(nm & 0xffffffffu);
    if (lane == 32) needw[wbase + 1] = (unsigned int)(nm >> 32);
    int seg = need ? cv : 0;
    int incl = seg;
#pragma unroll
    for (int d = 1; d < 64; d <<= 1) {
        int t2 = __shfl_up(incl, d);
        if (lane >= d) incl += t2;
    }
    int excl = incl - seg;
    int wave_total = __shfl(incl, 63);
    int rank = __popcll(nm & ((1ull << lane) - 1));
    int wcnt = __popcll(nm);
    int base_id = 0, base_off = 0;
    if (lane == 0) {
        if (wcnt > 0)       base_id  = atomicAdd(nflag, wcnt);
        if (wave_total > 0) base_off = atomicAdd(total, wave_total);
    }
    base_id  = __shfl(base_id, 0);
    base_off = __shfl(base_off, 0);
    if (need) {
        needlist[base_id + rank] = v;
        int o = base_off + excl;
        offs[v] = o;
        cursor[v] = o;
    }
}

// ---------------- k_scatter: filtered to needed cols via L1-resident bitmask;
//   srowp[pos] = pk[row] (single 8B gather, bit-identical to old {x[r], dr});
//   fold wagg edge terms (flagged edges only) using pk-packed dinv values.
__global__ void k_scatter(const int* __restrict__ row, const int* __restrict__ col,
                          const unsigned int* __restrict__ needw,
                          const unsigned int* __restrict__ flagbits,
                          const int* __restrict__ count,
                          const int2* __restrict__ pk,
                          int* cursor, int2* srowp, float* wagg, int ne) {
    int e = blockIdx.x * blockDim.x + threadIdx.x;
    if (e < ne) {
        int c = col[e];
        if ((needw[c >> 5] >> (c & 31)) & 1u) {
            int r = row[e];
            int pos = atomicAdd(&cursor[c], 1);
            int2 pr = pk[r];
            srowp[pos] = pr;
            if ((flagbits[c >> 5] >> (c & 31)) & 1u) {    // ~2% of edges
                float dc = __int_as_float(pk[c].y);
                float dr = __int_as_float(pr.y);
                atomicAdd(&wagg[r], (float)count[c] * dc * dr);
            }
        }
    }
}

// -------------------- fused conv1+conv2 over needed nodes (proven body):
//   wsum += wagg[v] * relu( b1 + dv^2*embW1[x[v]] + sum_e d_r*dv*embW1[x_r] )
__global__ void k_fconv(const int* __restrict__ needlist, const int* __restrict__ nneed_p,
                        const float* __restrict__ wagg, const int* __restrict__ x,
                        const int2* __restrict__ srowp,
                        const int* __restrict__ offs, const int* __restrict__ cnt,
                        const float* __restrict__ embW1, const float* __restrict__ b1,
                        float* __restrict__ wsum) {
    int lane = threadIdx.x & 63;
    int wib  = threadIdx.x >> 6;
    int wid  = blockIdx.x * (blockDim.x >> 6) + wib;
    int nw   = gridDim.x * (blockDim.x >> 6);
    int nn   = *nneed_p;
    const float4* __restrict__ ew = (const float4*)embW1;   // row r = ew + r*64
    float4 bfrag = ((const float4*)b1)[lane];
    float4 acc2 = {0.0f, 0.0f, 0.0f, 0.0f};

    for (int i = wid; i < nn; i += nw) {
        int v = needlist[i];
        int cv = cnt[v];
        float dv = rsqrtf((float)cv + 1.0f);
        float wa = wagg[v];
        float4 s = ew[(size_t)x[v] * 64 + lane];
        float w0 = dv * dv;
        float4 acc;
        acc.x = bfrag.x + w0 * s.x;
        acc.y = bfrag.y + w0 * s.y;
        acc.z = bfrag.z + w0 * s.z;
        acc.w = bfrag.w + w0 * s.w;
        int start = offs[v], m = cv;
        for (int base = 0; base < m; base += 64) {
            int mm = min(64, m - base);
            int xr = 0; float wr = 0.0f;
            if (lane < mm) {
                int2 pk2 = srowp[start + base + lane];      // one 8B load
                xr = pk2.x;
                wr = __int_as_float(pk2.y) * dv;
            }
            int e = 0;
            for (; e + 4 <= mm; e += 4) {
                int i0 = __shfl(xr, e),     i1 = __shfl(xr, e + 1);
                int i2 = __shfl(xr, e + 2), i3 = __shfl(xr, e + 3);
                float q0 = __shfl(wr, e),     q1 = __shfl(wr, e + 1);
                float q2 = __shfl(wr, e + 2), q3 = __shfl(wr, e + 3);
                float4 t0 = ew[(size_t)i0 * 64 + lane];
                float4 t1 = ew[(size_t)i1 * 64 + lane];
                float4 t2 = ew[(size_t)i2 * 64 + lane];
                float4 t3 = ew[(size_t)i3 * 64 + lane];
                acc.x += q0 * t0.x + q1 * t1.x + q2 * t2.x + q3 * t3.x;
                acc.y += q0 * t0.y + q1 * t1.y + q2 * t2.y + q3 * t3.y;
                acc.z += q0 * t0.z + q1 * t1.z + q2 * t2.z + q3 * t3.z;
                acc.w += q0 * t0.w + q1 * t1.w + q2 * t2.w + q3 * t3.w;
            }
            for (; e < mm; e++) {
                int i0 = __shfl(xr, e);
                float q0 = __shfl(wr, e);
                float4 t0 = ew[(size_t)i0 * 64 + lane];
                acc.x += q0 * t0.x;
                acc.y += q0 * t0.y;
                acc.z += q0 * t0.z;
                acc.w += q0 * t0.w;
            }
        }
        acc2.x += wa * fmaxf(acc.x, 0.0f);
        acc2.y += wa * fmaxf(acc.y, 0.0f);
        acc2.z += wa * fmaxf(acc.z, 0.0f);
        acc2.w += wa * fmaxf(acc.w, 0.0f);
    }

    __shared__ float red[4][H1D];
    red[wib][4 * lane + 0] = acc2.x;
    red[wib][4 * lane + 1] = acc2.y;
    red[wib][4 * lane + 2] = acc2.z;
    red[wib][4 * lane + 3] = acc2.w;
    __syncthreads();
    int t = threadIdx.x;
    float ssum = red[0][t] + red[1][t] + red[2][t] + red[3][t];
    atomicAdd(&wsum[(blockIdx.x & (NSL - 1)) * H1D + t], ssum);
}

// ---------- k_zout: 64 blocks (was 16). Each block: reduce wsum slices, compute
// z = b2 + (ws@W2)/NP (redundant per block, tiny), then 64 output cols with a
// 4-way j-split + LDS reduce. 4x more CUs streaming Wc.
__global__ void k_zout(const float* __restrict__ wsum, const float* __restrict__ W2,
                       const float* __restrict__ b2, const float* __restrict__ Wc,
                       const float* __restrict__ bc, float* __restrict__ out,
                       float inv_np) {
    __shared__ float ws[H1D];
    __shared__ float z[H2D];
    __shared__ float red[256];
    int t = threadIdx.x;
    float s = 0.0f;
#pragma unroll
    for (int c2 = 0; c2 < NSL; c2++) s += wsum[c2 * H1D + t];
    ws[t] = s;
    __syncthreads();
    if (t < H2D) {
        float acc = 0.0f;
#pragma unroll 8
        for (int k = 0; k < H1D; k++) acc += ws[k] * W2[k * H2D + t];
        z[t] = b2[t] + acc * inv_np;
    }
    __syncthreads();
    int c  = blockIdx.x * 64 + (t & 63);
    int ks = t >> 6;                       // 0..3
    float acc = 0.0f;
#pragma unroll 8
    for (int j = ks * 32; j < ks * 32 + 32; j++) acc += z[j] * Wc[(size_t)j * VOC + c];
    red[t] = acc;
    __syncthreads();
    if (t < 64) {
        int cc = blockIdx.x * 64 + t;
        out[cc] = bc[cc] + red[t] + red[t + 64] + red[t + 128] + red[t + 192];
    }
}

extern "C" void kernel_launch(void* const* d_in, const int* in_sizes, int n_in,
                              void* d_out, int out_size, void* d_ws, size_t ws_size,
                              hipStream_t stream) {
    const int n  = in_sizes[0];
    const int ne = in_sizes[1] / 2;
    const int np = in_sizes[2];

    const int*   x    = (const int*)d_in[0];
    const int*   ei   = (const int*)d_in[1];
    const int*   xpos = (const int*)d_in[2];
    const float* emb  = (const float*)d_in[3];
    const float* W1   = (const float*)d_in[4];
    const float* b1   = (const float*)d_in[5];
    const float* W2   = (const float*)d_in[6];
    const float* b2   = (const float*)d_in[7];
    const float* Wc   = (const float*)d_in[8];
    const float* bc   = (const float*)d_in[9];
    float*       out  = (float*)d_out;

    const int* row = ei;       // edge_index[0]
    const int* col = ei + ne;  // edge_index[1]

    char* p = (char*)d_ws;
    auto alloc = [&](size_t bytes) {
        char* r = p;
        p += (bytes + 255) & ~(size_t)255;
        return r;
    };
    const int nb     = (n + 255) / 256;
    const int neb    = (ne + 255) / 256;
    const int nwords = nb * 8;   // (nb*256)/32 — padded so ballot stores stay in-bounds

    int*          cnt      = (int*)alloc((size_t)n * 4);
    int*          offs     = (int*)alloc((size_t)n * 4);
    int*          cursor   = (int*)alloc((size_t)n * 4);
    int*          count    = (int*)alloc((size_t)n * 4);
    int*          needlist = (int*)alloc((size_t)n * 4);
    unsigned int* needw    = (unsigned int*)alloc((size_t)nwords * 4);
    unsigned int* flagbits = (unsigned int*)alloc((size_t)nwords * 4);
    int2*         srowp    = (int2*)alloc((size_t)ne * 8);
    int2*         pk       = (int2*)alloc((size_t)n * 8);
    int*          nflag    = (int*)alloc(256 * 4);
    int*          total    = (int*)alloc(256 * 4);
    float*        wagg     = (float*)alloc((size_t)n * 4);
    float*        embW1    = (float*)alloc((size_t)VOC * H1D * 4);
    float*        wsum     = (float*)alloc((size_t)NSL * H1D * 4);

    kA_init<<<nb, 256, 0, stream>>>(cnt, count, flagbits, needw, wagg, wsum,
                                    nflag, total, xpos, n, nwords, np);
    kB_embW1_hist<<<KB_GRID, 256, 0, stream>>>(emb, W1, embW1, row, col, flagbits,
                                               cnt, needw, ne);
    k_alloc<<<nb, 256, 0, stream>>>(needw, flagbits, cnt, count, x, wagg,
                                    needlist, nflag, total, offs, cursor, pk, n);
    k_scatter<<<neb, 256, 0, stream>>>(row, col, needw, flagbits, count, pk,
                                       cursor, srowp, wagg, ne);
    k_fconv<<<2048, 256, 0, stream>>>(needlist, nflag, wagg, x, srowp, offs, cnt,
                                      embW1, b1, wsum);
    k_zout<<<VOC / 64, 256, 0, stream>>>(wsum, W2, b2, Wc, bc, out, 1.0f / (float)np);
}

// Round 3
// 183.874 us; speedup vs baseline: 4.2634x; 1.0206x over previous
//
#include <hip/hip_runtime.h>

constexpr int EMB  = 128;   // EMB_DIM
constexpr int H1D  = 256;   // 2*HIDDEN
constexpr int H2D  = 128;   // HIDDEN
constexpr int VOC  = 4096;  // VOCAB
constexpr int NSL  = 32;    // wsum slices (atomic-contention spreading)
constexpr int RPB  = 4;     // emb rows per tile in embW1 GEMM (small tile -> 1024
                            // tiles -> 7 blocks/CU co-resident, latency hidden)

// ---------------- kA: zero state; block 0 builds flagbits + count from x_position.
// flagbits/count are zeroed and atomically built inside the SAME block (block 0),
// so there is no cross-block ordering hazard.
__global__ void kA_init(int* cnt, int* count, unsigned int* flagbits, unsigned int* needw,
                        float* wagg, float* wsum, int* nflag, int* total,
                        const int* __restrict__ xpos,
                        int n, int nwords, int np) {
    int t = threadIdx.x;
    if (blockIdx.x == 0) {
        for (int i = t; i < nwords; i += 256) flagbits[i] = 0u;
        for (int i = t; i < n; i += 256) count[i] = 0;
        __syncthreads();
        for (int i = t; i < np; i += 256) {
            int v = xpos[i];
            atomicAdd(&count[v], 1);
            atomicOr(&flagbits[v >> 5], 1u << (v & 31));
        }
        if (t == 0) { *nflag = 0; *total = 0; }
    } else {
        const int stride = (gridDim.x - 1) * 256;
        const int i0 = (blockIdx.x - 1) * 256 + t;
        for (int i = i0; i < n; i += stride) { cnt[i] = 0; wagg[i] = 0.0f; }
        for (int i = i0; i < nwords; i += stride) needw[i] = 0u;
        for (int i = i0; i < NSL * H1D; i += stride) wsum[i] = 0.0f;
    }
}

// ---------------- kB: blocks [0,1024) embW1 = emb @ W1 (one 4-row tile each)
//                   || blocks [1024,1792) in-degree histogram + needed-row marks.
// 1792 blocks = 7/CU, all co-resident (2KB LDS, 64 VGPR): the GEMM is
// throughput-bound (~4-5us) instead of latency-starved, hist overlaps it.
constexpr int GEMM_B  = VOC / RPB;          // 1024
constexpr int HIST_B  = 768;
constexpr int KB_GRID = GEMM_B + HIST_B;    // 1792 = 7 blocks/CU
__global__ __launch_bounds__(256) void kB_embW1_hist(
        const float* __restrict__ emb, const float* __restrict__ W1,
        float* __restrict__ embW1,
        const int* __restrict__ row, const int* __restrict__ col,
        const unsigned int* __restrict__ flagbits,
        int* cnt, unsigned int* markw, int ne) {
    int t = threadIdx.x;
    if (blockIdx.x < GEMM_B) {
        __shared__ float er[RPB][EMB];   // 2 KB
        int r0 = blockIdx.x * RPB;
        for (int i = t; i < RPB * EMB; i += 256)
            er[i / EMB][i % EMB] = emb[(size_t)r0 * EMB + i];
        __syncthreads();
        float acc[RPB];
#pragma unroll
        for (int rr = 0; rr < RPB; rr++) acc[rr] = 0.0f;
        for (int k = 0; k < EMB; k++) {
            float w = W1[k * H1D + t];
#pragma unroll
            for (int rr = 0; rr < RPB; rr++) acc[rr] += er[rr][k] * w;
        }
#pragma unroll
        for (int rr = 0; rr < RPB; rr++)
            embW1[(size_t)(r0 + rr) * H1D + t] = acc[rr];
    } else {
        const int stride = HIST_B * 256;
        for (int e = (blockIdx.x - GEMM_B) * 256 + t; e < ne; e += stride) {
            int c = col[e];
            atomicAdd(&cnt[c], 1);
            if ((flagbits[c >> 5] >> (c & 31)) & 1u) {   // ~2% of edges
                int r = row[e];
                atomicOr(&markw[r >> 5], 1u << (r & 31));
            }
        }
    }
}

// ------- k_alloc: need = mark||flag; canonical needbits via wave-ballot plain store;
//         CSR bump-alloc (wave-aggregated atomics); wagg self term;
//         packed pk[v] = {x[v], rsqrt(cnt[v]+1)} so scatter does 1 gather not 2.
__global__ void k_alloc(unsigned int* needw,
                        const unsigned int* __restrict__ flagbits,
                        const int* __restrict__ cnt, const int* __restrict__ count,
                        const int* __restrict__ x,
                        float* wagg, int* needlist, int* nflag, int* total,
                        int* offs, int* cursor, int2* pk, int n) {
    int v = blockIdx.x * blockDim.x + threadIdx.x;
    int lane = threadIdx.x & 63;
    int cv = 0;
    bool need = false;
    if (v < n) {
        cv = cnt[v];
        float dv = rsqrtf((float)cv + 1.0f);
        int2 p; p.x = x[v]; p.y = __float_as_int(dv);
        pk[v] = p;
        bool mark = (needw[v >> 5] >> (v & 31)) & 1u;
        bool flag = (flagbits[v >> 5] >> (v & 31)) & 1u;
        need = mark || flag;
        if (flag) wagg[v] = (float)count[v] / ((float)cv + 1.0f);  // count*dinv^2
    }
    // canonical needbits: ballot -> one word per half-wave, plain store by owner lane
    unsigned long long nm = __ballot(need);
    int wbase = (v & ~63) >> 5;            // v is wave-aligned at lane 0
    if (lane == 0)  needw[wbase]     = (unsigned int)(nm & 0xffffffffu);
    if (lane == 32) needw[wbase + 1] = (unsigned int)(nm >> 32);
    int seg = need ? cv : 0;
    int incl = seg;
#pragma unroll
    for (int d = 1; d < 64; d <<= 1) {
        int t2 = __shfl_up(incl, d);
        if (lane >= d) incl += t2;
    }
    int excl = incl - seg;
    int wave_total = __shfl(incl, 63);
    int rank = __popcll(nm & ((1ull << lane) - 1));
    int wcnt = __popcll(nm);
    int base_id = 0, base_off = 0;
    if (lane == 0) {
        if (wcnt > 0)       base_id  = atomicAdd(nflag, wcnt);
        if (wave_total > 0) base_off = atomicAdd(total, wave_total);
    }
    base_id  = __shfl(base_id, 0);
    base_off = __shfl(base_off, 0);
    if (need) {
        needlist[base_id + rank] = v;
        int o = base_off + excl;
        offs[v] = o;
        cursor[v] = o;
    }
}

// ---------------- k_scatter: filtered to needed cols via L1-resident bitmask;
//   srowp[pos] = pk[row] (single 8B gather); wagg edge terms (flagged only).
__global__ void k_scatter(const int* __restrict__ row, const int* __restrict__ col,
                          const unsigned int* __restrict__ needw,
                          const unsigned int* __restrict__ flagbits,
                          const int* __restrict__ count,
                          const int2* __restrict__ pk,
                          int* cursor, int2* srowp, float* wagg, int ne) {
    int e = blockIdx.x * blockDim.x + threadIdx.x;
    if (e < ne) {
        int c = col[e];
        if ((needw[c >> 5] >> (c & 31)) & 1u) {
            int r = row[e];
            int pos = atomicAdd(&cursor[c], 1);
            int2 pr = pk[r];
            srowp[pos] = pr;
            if ((flagbits[c >> 5] >> (c & 31)) & 1u) {    // ~2% of edges
                float dc = __int_as_float(pk[c].y);
                float dr = __int_as_float(pr.y);
                atomicAdd(&wagg[r], (float)count[c] * dc * dr);
            }
        }
    }
}

// -------------------- fused conv1+conv2 over needed nodes (proven body):
//   wsum += wagg[v] * relu( b1 + dv^2*embW1[x[v]] + sum_e d_r*dv*embW1[x_r] )
__global__ void k_fconv(const int* __restrict__ needlist, const int* __restrict__ nneed_p,
                        const float* __restrict__ wagg, const int* __restrict__ x,
                        const int2* __restrict__ srowp,
                        const int* __restrict__ offs, const int* __restrict__ cnt,
                        const float* __restrict__ embW1, const float* __restrict__ b1,
                        float* __restrict__ wsum) {
    int lane = threadIdx.x & 63;
    int wib  = threadIdx.x >> 6;
    int wid  = blockIdx.x * (blockDim.x >> 6) + wib;
    int nw   = gridDim.x * (blockDim.x >> 6);
    int nn   = *nneed_p;
    const float4* __restrict__ ew = (const float4*)embW1;   // row r = ew + r*64
    float4 bfrag = ((const float4*)b1)[lane];
    float4 acc2 = {0.0f, 0.0f, 0.0f, 0.0f};

    for (int i = wid; i < nn; i += nw) {
        int v = needlist[i];
        int cv = cnt[v];
        float dv = rsqrtf((float)cv + 1.0f);
        float wa = wagg[v];
        float4 s = ew[(size_t)x[v] * 64 + lane];
        float w0 = dv * dv;
        float4 acc;
        acc.x = bfrag.x + w0 * s.x;
        acc.y = bfrag.y + w0 * s.y;
        acc.z = bfrag.z + w0 * s.z;
        acc.w = bfrag.w + w0 * s.w;
        int start = offs[v], m = cv;
        for (int base = 0; base < m; base += 64) {
            int mm = min(64, m - base);
            int xr = 0; float wr = 0.0f;
            if (lane < mm) {
                int2 pk2 = srowp[start + base + lane];      // one 8B load
                xr = pk2.x;
                wr = __int_as_float(pk2.y) * dv;
            }
            int e = 0;
            for (; e + 4 <= mm; e += 4) {
                int i0 = __shfl(xr, e),     i1 = __shfl(xr, e + 1);
                int i2 = __shfl(xr, e + 2), i3 = __shfl(xr, e + 3);
                float q0 = __shfl(wr, e),     q1 = __shfl(wr, e + 1);
                float q2 = __shfl(wr, e + 2), q3 = __shfl(wr, e + 3);
                float4 t0 = ew[(size_t)i0 * 64 + lane];
                float4 t1 = ew[(size_t)i1 * 64 + lane];
                float4 t2 = ew[(size_t)i2 * 64 + lane];
                float4 t3 = ew[(size_t)i3 * 64 + lane];
                acc.x += q0 * t0.x + q1 * t1.x + q2 * t2.x + q3 * t3.x;
                acc.y += q0 * t0.y + q1 * t1.y + q2 * t2.y + q3 * t3.y;
                acc.z += q0 * t0.z + q1 * t1.z + q2 * t2.z + q3 * t3.z;
                acc.w += q0 * t0.w + q1 * t1.w + q2 * t2.w + q3 * t3.w;
            }
            for (; e < mm; e++) {
                int i0 = __shfl(xr, e);
                float q0 = __shfl(wr, e);
                float4 t0 = ew[(size_t)i0 * 64 + lane];
                acc.x += q0 * t0.x;
                acc.y += q0 * t0.y;
                acc.z += q0 * t0.z;
                acc.w += q0 * t0.w;
            }
        }
        acc2.x += wa * fmaxf(acc.x, 0.0f);
        acc2.y += wa * fmaxf(acc.y, 0.0f);
        acc2.z += wa * fmaxf(acc.z, 0.0f);
        acc2.w += wa * fmaxf(acc.w, 0.0f);
    }

    __shared__ float red[4][H1D];
    red[wib][4 * lane + 0] = acc2.x;
    red[wib][4 * lane + 1] = acc2.y;
    red[wib][4 * lane + 2] = acc2.z;
    red[wib][4 * lane + 3] = acc2.w;
    __syncthreads();
    int t = threadIdx.x;
    float ssum = red[0][t] + red[1][t] + red[2][t] + red[3][t];
    atomicAdd(&wsum[(blockIdx.x & (NSL - 1)) * H1D + t], ssum);
}

// ---------- k_zout: 64 blocks. Each block: reduce wsum slices, compute
// z = b2 + (ws@W2)/NP (redundant per block, tiny), then 64 output cols with a
// 4-way j-split + LDS reduce.
__global__ void k_zout(const float* __restrict__ wsum, const float* __restrict__ W2,
                       const float* __restrict__ b2, const float* __restrict__ Wc,
                       const float* __restrict__ bc, float* __restrict__ out,
                       float inv_np) {
    __shared__ float ws[H1D];
    __shared__ float z[H2D];
    __shared__ float red[256];
    int t = threadIdx.x;
    float s = 0.0f;
#pragma unroll
    for (int c2 = 0; c2 < NSL; c2++) s += wsum[c2 * H1D + t];
    ws[t] = s;
    __syncthreads();
    if (t < H2D) {
        float acc = 0.0f;
#pragma unroll 8
        for (int k = 0; k < H1D; k++) acc += ws[k] * W2[k * H2D + t];
        z[t] = b2[t] + acc * inv_np;
    }
    __syncthreads();
    int c  = blockIdx.x * 64 + (t & 63);
    int ks = t >> 6;                       // 0..3
    float acc = 0.0f;
#pragma unroll 8
    for (int j = ks * 32; j < ks * 32 + 32; j++) acc += z[j] * Wc[(size_t)j * VOC + c];
    red[t] = acc;
    __syncthreads();
    if (t < 64) {
        int cc = blockIdx.x * 64 + t;
        out[cc] = bc[cc] + red[t] + red[t + 64] + red[t + 128] + red[t + 192];
    }
}

extern "C" void kernel_launch(void* const* d_in, const int* in_sizes, int n_in,
                              void* d_out, int out_size, void* d_ws, size_t ws_size,
                              hipStream_t stream) {
    const int n  = in_sizes[0];
    const int ne = in_sizes[1] / 2;
    const int np = in_sizes[2];

    const int*   x    = (const int*)d_in[0];
    const int*   ei   = (const int*)d_in[1];
    const int*   xpos = (const int*)d_in[2];
    const float* emb  = (const float*)d_in[3];
    const float* W1   = (const float*)d_in[4];
    const float* b1   = (const float*)d_in[5];
    const float* W2   = (const float*)d_in[6];
    const float* b2   = (const float*)d_in[7];
    const float* Wc   = (const float*)d_in[8];
    const float* bc   = (const float*)d_in[9];
    float*       out  = (float*)d_out;

    const int* row = ei;       // edge_index[0]
    const int* col = ei + ne;  // edge_index[1]

    char* p = (char*)d_ws;
    auto alloc = [&](size_t bytes) {
        char* r = p;
        p += (bytes + 255) & ~(size_t)255;
        return r;
    };
    const int nb     = (n + 255) / 256;
    const int neb    = (ne + 255) / 256;
    const int nwords = nb * 8;   // (nb*256)/32 — padded so ballot stores stay in-bounds

    int*          cnt      = (int*)alloc((size_t)n * 4);
    int*          offs     = (int*)alloc((size_t)n * 4);
    int*          cursor   = (int*)alloc((size_t)n * 4);
    int*          count    = (int*)alloc((size_t)n * 4);
    int*          needlist = (int*)alloc((size_t)n * 4);
    unsigned int* needw    = (unsigned int*)alloc((size_t)nwords * 4);
    unsigned int* flagbits = (unsigned int*)alloc((size_t)nwords * 4);
    int2*         srowp    = (int2*)alloc((size_t)ne * 8);
    int2*         pk       = (int2*)alloc((size_t)n * 8);
    int*          nflag    = (int*)alloc(256 * 4);
    int*          total    = (int*)alloc(256 * 4);
    float*        wagg     = (float*)alloc((size_t)n * 4);
    float*        embW1    = (float*)alloc((size_t)VOC * H1D * 4);
    float*        wsum     = (float*)alloc((size_t)NSL * H1D * 4);

    kA_init<<<nb, 256, 0, stream>>>(cnt, count, flagbits, needw, wagg, wsum,
                                    nflag, total, xpos, n, nwords, np);
    kB_embW1_hist<<<KB_GRID, 256, 0, stream>>>(emb, W1, embW1, row, col, flagbits,
                                               cnt, needw, ne);
    k_alloc<<<nb, 256, 0, stream>>>(needw, flagbits, cnt, count, x, wagg,
                                    needlist, nflag, total, offs, cursor, pk, n);
    k_scatter<<<neb, 256, 0, stream>>>(row, col, needw, flagbits, count, pk,
                                       cursor, srowp, wagg, ne);
    k_fconv<<<2048, 256, 0, stream>>>(needlist, nflag, wagg, x, srowp, offs, cnt,
                                      embW1, b1, wsum);
    k_zout<<<VOC / 64, 256, 0, stream>>>(wsum, W2, b2, Wc, bc, out, 1.0f / (float)np);
}